// Round 7
// baseline (718.571 us; speedup 1.0000x reference)
//
#include <hip/hip_runtime.h>

// VectorQuantizer forward: N=131072 rows of D=64 vs K=1024 codes.
// Outputs flat fp32: [quantized_st (N*D), loss (1), indices-as-float (N)].
//
// Two-tier exactness scheme (validated rounds 4-6, absmax 0):
//  - vq_main: bf16 hi/lo split MFMA approx of g[k] = e2[k] - 2*dot (row-const
//    x2 dropped; +0.5 bias makes g' positive so IEEE bits are monotonic).
//    Argmin over packed keys (g'-bits & ~1023) | idx  -> min_u32 == numpy
//    first-index rule. Rows with masked (sec - best) < MARGIN flagged.
//    Safety: unflagged => true gap >= MARGIN - 6.1e-5(mask) - 4e-6(approx) > 0.
//  - vq_cleanup: one wave per flagged row, bit-exact numerics (sequential
//    fmaf dot d=0..63, (x2+e2)-2*dot, u64 (dist,idx) key min = numpy rule).
// Main K-loop: no LDS, no barriers; B pre-swizzled to MFMA frag order,
// tile t+1 register-prefetched while tile t computes.

#define NROWS 131072
#define DIM 64
#define KCODES 1024
#define MARGIN 1.2e-4f
#define LOSS_SCALE (1.25f / ((float)NROWS * (float)DIM))

typedef short bf16x8 __attribute__((ext_vector_type(8)));
typedef short s16x4 __attribute__((ext_vector_type(4)));
typedef float f32x4 __attribute__((ext_vector_type(4)));

__device__ __forceinline__ short f2bf(float f) {
    unsigned u = __float_as_uint(f);
    u += 0x7FFF + ((u >> 16) & 1);   // RNE
    return (short)(u >> 16);
}
__device__ __forceinline__ float bf2f(short h) {
    return __uint_as_float(((unsigned)(unsigned short)h) << 16);
}

// Swizzle w into MFMA B-frag order, 16 threads per code (coalesced loads):
//   short index = ((((t*2+ct)*2+kc)*4+q)*16 + m)*8 + j
//   where k = t*32 + ct*16 + m, d = kc*32 + q*8 + j.
__global__ __launch_bounds__(256) void prep_swizzle(const float* __restrict__ w,
                                                    short* __restrict__ w_hi,
                                                    short* __restrict__ w_lo) {
    const int gid = blockIdx.x * 256 + threadIdx.x;
    const int k = gid >> 4, s = gid & 15;
    const float4 v = *(const float4*)(w + (size_t)k * DIM + s * 4);
    const int t = k >> 5, ct = (k >> 4) & 1, m = k & 15;
    const int kc = s >> 3, q = (s >> 1) & 3, j0 = (s & 1) * 4;
    const size_t fo =
        ((size_t)(((t * 2 + ct) * 2 + kc) * 4 + q) * 16 + m) * 8 + j0;
    float f[4] = {v.x, v.y, v.z, v.w};
    s16x4 hv, lv;
#pragma unroll
    for (int i = 0; i < 4; ++i) {
        short h = f2bf(f[i]);
        hv[i] = h;
        lv[i] = f2bf(f[i] - bf2f(h));
    }
    *(s16x4*)(w_hi + fo) = hv;
    *(s16x4*)(w_lo + fo) = lv;
}

// e2 by sequential fmaf (bit pattern the cleanup's exactness relies on);
// e2p = e2 + 0.5 is the biased constant for the packed-key argmin.
__global__ __launch_bounds__(256) void prep_e2(const float* __restrict__ w,
                                               float* __restrict__ e2,
                                               float* __restrict__ e2p) {
    int k = blockIdx.x * blockDim.x + threadIdx.x;
    if (k >= KCODES) return;
    const float* wk = w + (size_t)k * DIM;
    float s = 0.f;
#pragma unroll
    for (int d = 0; d < DIM; ++d) s = fmaf(wk[d], wk[d], s);
    e2[k] = s;
    e2p[k] = s + 0.5f;
}

// Block: 4 independent waves x 32 rows = 128 rows. No barriers in the K-loop.
__global__ __launch_bounds__(256, 2) void vq_main(
        const float* __restrict__ x, const float* __restrict__ w,
        const float* __restrict__ e2p,
        const short* __restrict__ w_hi, const short* __restrict__ w_lo,
        float* __restrict__ out_q, float* __restrict__ out_loss,
        float* __restrict__ out_idx,
        unsigned* __restrict__ flag_cnt, unsigned* __restrict__ flag_list) {
    const int tid = threadIdx.x;
    const int lane = tid & 63;
    const int wv = tid >> 6;
    const int m = lane & 15;
    const int q = lane >> 4;
    const int block_row0 = blockIdx.x * 128;
    const int wave_row0 = block_row0 + wv * 32;

    __shared__ int sidx[128];
    __shared__ unsigned char sflg[128];
    __shared__ float red[4];

    // ---- A operand: 2 rowtiles x 2 k-chunks; A[m][k=q*8+j] ----
    bf16x8 ah[2][2], al[2][2];
#pragma unroll
    for (int rt = 0; rt < 2; ++rt) {
        const float* xr = x + (size_t)(wave_row0 + rt * 16 + m) * DIM + q * 8;
        float xa[2][8];
        *(float4*)&xa[0][0] = *(const float4*)(xr);
        *(float4*)&xa[0][4] = *(const float4*)(xr + 4);
        *(float4*)&xa[1][0] = *(const float4*)(xr + 32);
        *(float4*)&xa[1][4] = *(const float4*)(xr + 36);
#pragma unroll
        for (int c = 0; c < 2; ++c)
#pragma unroll
            for (int j = 0; j < 8; ++j) {
                float f = xa[c][j];
                short h = f2bf(f);
                ah[rt][c][j] = h;
                al[rt][c][j] = f2bf(f - bf2f(h));
            }
    }

    unsigned best[2][4], sec[2][4];
#pragma unroll
    for (int rt = 0; rt < 2; ++rt)
#pragma unroll
        for (int r = 0; r < 4; ++r) { best[rt][r] = ~0u; sec[rt][r] = ~0u; }

    // Per-lane B pointers; tile stride 2048 shorts, frag stride 512.
    const short* ph = w_hi + q * 128 + m * 8;
    const short* pl = w_lo + q * 128 + m * 8;

    // Prime tile 0
    bf16x8 cbh[2][2], cbl[2][2];
    float ce[2];
#pragma unroll
    for (int ct = 0; ct < 2; ++ct)
#pragma unroll
        for (int kc = 0; kc < 2; ++kc) {
            cbh[ct][kc] = *(const bf16x8*)(ph + (ct * 2 + kc) * 512);
            cbl[ct][kc] = *(const bf16x8*)(pl + (ct * 2 + kc) * 512);
        }
    ce[0] = e2p[m];
    ce[1] = e2p[16 + m];

    unsigned id0 = (unsigned)m;   // code idx for (t, ct=0); ct=1 adds 16

    for (int t = 0; t < KCODES / 32; ++t) {
        // ---- prefetch tile t+1 (wraps at 31; harmless) ----
        const int tn = (t + 1) & 31;
        bf16x8 nbh[2][2], nbl[2][2];
        float ne[2];
#pragma unroll
        for (int ct = 0; ct < 2; ++ct)
#pragma unroll
            for (int kc = 0; kc < 2; ++kc) {
                int off = tn * 2048 + (ct * 2 + kc) * 512;
                nbh[ct][kc] = *(const bf16x8*)(ph + off);
                nbl[ct][kc] = *(const bf16x8*)(pl + off);
            }
        ne[0] = e2p[tn * 32 + m];
        ne[1] = e2p[tn * 32 + 16 + m];

        // ---- MFMA on current tile ----
        f32x4 acc[2][2];
#pragma unroll
        for (int rt = 0; rt < 2; ++rt)
#pragma unroll
            for (int ct = 0; ct < 2; ++ct) {
                f32x4 a = {0.f, 0.f, 0.f, 0.f};
                a = __builtin_amdgcn_mfma_f32_16x16x32_bf16(al[rt][0], cbh[ct][0], a, 0, 0, 0);
                a = __builtin_amdgcn_mfma_f32_16x16x32_bf16(ah[rt][0], cbl[ct][0], a, 0, 0, 0);
                a = __builtin_amdgcn_mfma_f32_16x16x32_bf16(ah[rt][0], cbh[ct][0], a, 0, 0, 0);
                a = __builtin_amdgcn_mfma_f32_16x16x32_bf16(al[rt][1], cbh[ct][1], a, 0, 0, 0);
                a = __builtin_amdgcn_mfma_f32_16x16x32_bf16(ah[rt][1], cbl[ct][1], a, 0, 0, 0);
                a = __builtin_amdgcn_mfma_f32_16x16x32_bf16(ah[rt][1], cbh[ct][1], a, 0, 0, 0);
                acc[rt][ct] = a;
            }

        // ---- packed-key argmin epilogue ----
#pragma unroll
        for (int rt = 0; rt < 2; ++rt)
#pragma unroll
            for (int ct = 0; ct < 2; ++ct) {
                float e2c = ce[ct];
                unsigned idc = id0 + (unsigned)(ct * 16);
#pragma unroll
                for (int r = 0; r < 4; ++r) {
                    float g = fmaf(-2.f, acc[rt][ct][r], e2c);  // > 0 always
                    unsigned kb = (__float_as_uint(g) & 0xFFFFFC00u) | idc;
                    unsigned mx = kb > best[rt][r] ? kb : best[rt][r];
                    sec[rt][r] = sec[rt][r] < mx ? sec[rt][r] : mx;
                    best[rt][r] = kb < best[rt][r] ? kb : best[rt][r];
                }
            }
        id0 += 32;

        // rotate prefetch
#pragma unroll
        for (int ct = 0; ct < 2; ++ct)
#pragma unroll
            for (int kc = 0; kc < 2; ++kc) {
                cbh[ct][kc] = nbh[ct][kc];
                cbl[ct][kc] = nbl[ct][kc];
            }
        ce[0] = ne[0];
        ce[1] = ne[1];
    }

    // cross-lane min over the 16 m-lanes (same q group)
#pragma unroll
    for (int off = 1; off < 16; off <<= 1)
#pragma unroll
        for (int rt = 0; rt < 2; ++rt)
#pragma unroll
            for (int r = 0; r < 4; ++r) {
                unsigned ob = (unsigned)__shfl_xor((int)best[rt][r], off, 64);
                unsigned os = (unsigned)__shfl_xor((int)sec[rt][r], off, 64);
                unsigned mx = ob > best[rt][r] ? ob : best[rt][r];
                unsigned s2 = sec[rt][r] < os ? sec[rt][r] : os;
                sec[rt][r] = s2 < mx ? s2 : mx;
                best[rt][r] = ob < best[rt][r] ? ob : best[rt][r];
            }

    if (m == 0) {
#pragma unroll
        for (int rt = 0; rt < 2; ++rt)
#pragma unroll
            for (int r = 0; r < 4; ++r) {
                int lr = wv * 32 + rt * 16 + q * 4 + r;
                unsigned bk = best[rt][r], sk = sec[rt][r];
                int bi = (int)(bk & 1023u);
                float bf = __uint_as_float(bk & 0xFFFFFC00u);
                float sf = __uint_as_float(sk & 0xFFFFFC00u);
                bool fl = (sf - bf) < MARGIN;
                sidx[lr] = bi;
                sflg[lr] = fl ? 1 : 0;
                if (fl) {
                    unsigned p = atomicAdd(flag_cnt, 1u);
                    flag_list[p] = (unsigned)(block_row0 + lr);
                }
            }
    }
    __syncthreads();

    // ---- output pass: 2 x 64 rows, 4 threads/row ----
    float lsum = 0.f;
    const int rl = tid >> 2, part = tid & 3;
#pragma unroll
    for (int p = 0; p < 2; ++p) {
        int lr = p * 64 + rl;
        int grow = block_row0 + lr;
        if (!sflg[lr]) {
            int bi = sidx[lr];
            const float* xs = x + (size_t)grow * DIM + part * 16;
            const float* ws = w + (size_t)bi * DIM + part * 16;
            float* os = out_q + (size_t)grow * DIM + part * 16;
#pragma unroll
            for (int i = 0; i < 4; ++i) {
                float4 xv = *(const float4*)(xs + 4 * i);
                float4 wv4 = *(const float4*)(ws + 4 * i);
                float d0 = wv4.x - xv.x, d1 = wv4.y - xv.y;
                float d2 = wv4.z - xv.z, d3 = wv4.w - xv.w;
                lsum = fmaf(d0, d0, lsum);
                lsum = fmaf(d1, d1, lsum);
                lsum = fmaf(d2, d2, lsum);
                lsum = fmaf(d3, d3, lsum);
                float4 o = {xv.x + d0, xv.y + d1, xv.z + d2, xv.w + d3};
                *(float4*)(os + 4 * i) = o;
            }
            if (part == 0) out_idx[grow] = (float)bi;
        }
    }

    for (int off = 32; off > 0; off >>= 1) lsum += __shfl_down(lsum, off, 64);
    if ((tid & 63) == 0) red[tid >> 6] = lsum;
    __syncthreads();
    if (tid == 0) {
        float s = (red[0] + red[1]) + (red[2] + red[3]);
        atomicAdd(out_loss, s * LOSS_SCALE);
    }
}

// Exact re-scan: ONE WAVE PER FLAGGED ROW, no LDS. Each lane owns 16 codes
// (4 independent sequential-d fmaf chains at a time); u64 (dist,idx) key min
// across lane and wave = numpy first-index argmin. Bit-exact numerics.
__global__ __launch_bounds__(256) void vq_cleanup(
        const float* __restrict__ x, const float* __restrict__ w,
        const float* __restrict__ e2,
        const unsigned* __restrict__ flag_cnt,
        const unsigned* __restrict__ flag_list,
        float* __restrict__ out_q, float* __restrict__ out_loss,
        float* __restrict__ out_idx) {
    const int lane = threadIdx.x & 63;
    const unsigned gw = blockIdx.x * 4 + (threadIdx.x >> 6);
    const unsigned nw = gridDim.x * 4;
    const unsigned cnt = *flag_cnt;

    for (unsigned i = gw; i < cnt; i += nw) {
        const int row = (int)__builtin_amdgcn_readfirstlane((int)flag_list[i]);
        const float* xr = x + (size_t)row * DIM;   // wave-uniform -> s_loads

        // x2: sequential fmaf over d (bit pattern matches reference path)
        float x2 = 0.f;
#pragma unroll
        for (int d = 0; d < DIM; ++d) x2 = fmaf(xr[d], xr[d], x2);

        unsigned long long kmin = ~0ULL;
        const int k0 = lane * 16;
#pragma unroll
        for (int jg = 0; jg < 4; ++jg) {
            const float* w0 = w + (size_t)(k0 + jg * 4 + 0) * DIM;
            const float* w1 = w + (size_t)(k0 + jg * 4 + 1) * DIM;
            const float* w2 = w + (size_t)(k0 + jg * 4 + 2) * DIM;
            const float* w3 = w + (size_t)(k0 + jg * 4 + 3) * DIM;
            float dot0 = 0.f, dot1 = 0.f, dot2 = 0.f, dot3 = 0.f;
#pragma unroll
            for (int d4 = 0; d4 < 16; ++d4) {
                float4 xv = *(const float4*)(xr + d4 * 4);
                float4 a = *(const float4*)(w0 + d4 * 4);
                float4 b = *(const float4*)(w1 + d4 * 4);
                float4 c = *(const float4*)(w2 + d4 * 4);
                float4 e = *(const float4*)(w3 + d4 * 4);
                dot0 = fmaf(a.x, xv.x, dot0); dot0 = fmaf(a.y, xv.y, dot0);
                dot0 = fmaf(a.z, xv.z, dot0); dot0 = fmaf(a.w, xv.w, dot0);
                dot1 = fmaf(b.x, xv.x, dot1); dot1 = fmaf(b.y, xv.y, dot1);
                dot1 = fmaf(b.z, xv.z, dot1); dot1 = fmaf(b.w, xv.w, dot1);
                dot2 = fmaf(c.x, xv.x, dot2); dot2 = fmaf(c.y, xv.y, dot2);
                dot2 = fmaf(c.z, xv.z, dot2); dot2 = fmaf(c.w, xv.w, dot2);
                dot3 = fmaf(e.x, xv.x, dot3); dot3 = fmaf(e.y, xv.y, dot3);
                dot3 = fmaf(e.z, xv.z, dot3); dot3 = fmaf(e.w, xv.w, dot3);
            }
            float dd[4] = {dot0, dot1, dot2, dot3};
#pragma unroll
            for (int c2 = 0; c2 < 4; ++c2) {
                int code = k0 + jg * 4 + c2;
                float dist = (x2 + e2[code]) - 2.0f * dd[c2];
                unsigned long long key =
                    ((unsigned long long)__float_as_uint(dist) << 32) |
                    (unsigned)code;
                kmin = kmin < key ? kmin : key;
            }
        }
        // full-wave butterfly min
#pragma unroll
        for (int off = 1; off < 64; off <<= 1) {
            unsigned long long o = __shfl_xor(kmin, off, 64);
            kmin = kmin < o ? kmin : o;
        }
        const int bi = (int)(unsigned)(kmin & 0xFFFFFFFFu);

        if (lane < 16) {
            float4 x4 = *(const float4*)(xr + lane * 4);
            float4 w4 = *(const float4*)(w + (size_t)bi * DIM + lane * 4);
            float d0 = w4.x - x4.x, d1 = w4.y - x4.y;
            float d2 = w4.z - x4.z, d3 = w4.w - x4.w;
            float ls = 0.f;
            ls = fmaf(d0, d0, ls);
            ls = fmaf(d1, d1, ls);
            ls = fmaf(d2, d2, ls);
            ls = fmaf(d3, d3, ls);
            float4 o = {x4.x + d0, x4.y + d1, x4.z + d2, x4.w + d3};
            *(float4*)(out_q + (size_t)row * DIM + lane * 4) = o;
#pragma unroll
            for (int off = 1; off < 16; off <<= 1)
                ls += __shfl_xor(ls, off, 64);
            if (lane == 0) {
                out_idx[row] = (float)bi;
                atomicAdd(out_loss, ls * LOSS_SCALE);
            }
        }
    }
}

extern "C" void kernel_launch(void* const* d_in, const int* in_sizes, int n_in,
                              void* d_out, int out_size, void* d_ws, size_t ws_size,
                              hipStream_t stream) {
    const float* x = (const float*)d_in[0];   // [N, D]
    const float* w = (const float*)d_in[1];   // [K, D]

    float* out_q    = (float*)d_out;
    float* out_loss = (float*)d_out + (size_t)NROWS * DIM;
    float* out_idx  = out_loss + 1;

    // ws: e2 (4KB) | e2p (4KB) | w_hi (128KB) | w_lo (128KB) | cnt | list
    float* e2 = (float*)d_ws;
    float* e2p = e2 + KCODES;
    short* w_hi = (short*)(e2p + KCODES);
    short* w_lo = w_hi + (size_t)KCODES * DIM;
    unsigned* cnt = (unsigned*)(w_lo + (size_t)KCODES * DIM);
    unsigned* list = cnt + 1;

    hipMemsetAsync(out_loss, 0, sizeof(float), stream);
    hipMemsetAsync(cnt, 0, sizeof(unsigned), stream);

    prep_swizzle<<<KCODES * 16 / 256, 256, 0, stream>>>(w, w_hi, w_lo);
    prep_e2<<<(KCODES + 255) / 256, 256, 0, stream>>>(w, e2, e2p);
    vq_main<<<NROWS / 128, 256, 0, stream>>>(x, w, e2p, w_hi, w_lo,
                                             out_q, out_loss, out_idx, cnt, list);
    vq_cleanup<<<2048, 256, 0, stream>>>(x, w, e2, cnt, list,
                                         out_q, out_loss, out_idx);
}

// Round 8
// 398.437 us; speedup vs baseline: 1.8035x; 1.8035x over previous
//
#include <hip/hip_runtime.h>

// VectorQuantizer forward: N=131072 rows of D=64 vs K=1024 codes.
// Outputs flat fp32: [quantized_st (N*D), loss (1), indices-as-float (N)].
//
// Two-tier exactness scheme (validated rounds 4-7, absmax 0):
//  - vq_main: bf16 hi/lo split MFMA approx of g[k] = e2[k] - 2*dot (row-const
//    x2 dropped; +0.5 bias makes g' positive so IEEE bits are monotonic).
//    Argmin over packed keys (g'-bits & ~1023) | idx  -> min_u32 == numpy
//    first-index rule. Rows with masked (sec - best) < MARGIN flagged.
//    Safety: unflagged => true gap >= MARGIN - 6.1e-5(mask) - 8e-6(approx) > 0.
//  - vq_cleanup: one wave per flagged row, bit-exact numerics (sequential
//    fmaf dot d=0..63, (x2+e2)-2*dot, u64 (dist,idx) key min = numpy rule).
//    NOTE (round-7 lesson): do NOT fully unroll the code loop — hoisted loads
//    blow past 256 VGPRs and scratch-spill ~200KB/row (793MB WRITE_SIZE).
// Main K-loop: no LDS, no barriers; B pre-swizzled to MFMA frag order,
// tile t+1 register-prefetched while tile t computes.

#define NROWS 131072
#define DIM 64
#define KCODES 1024
#define MARGIN 1.2e-4f
#define LOSS_SCALE (1.25f / ((float)NROWS * (float)DIM))

typedef short bf16x8 __attribute__((ext_vector_type(8)));
typedef short s16x4 __attribute__((ext_vector_type(4)));
typedef float f32x4 __attribute__((ext_vector_type(4)));

__device__ __forceinline__ short f2bf(float f) {
    unsigned u = __float_as_uint(f);
    u += 0x7FFF + ((u >> 16) & 1);   // RNE
    return (short)(u >> 16);
}
__device__ __forceinline__ float bf2f(short h) {
    return __uint_as_float(((unsigned)(unsigned short)h) << 16);
}

// Swizzle w into MFMA B-frag order, 16 threads per code (coalesced loads):
//   short index = ((((t*2+ct)*2+kc)*4+q)*16 + m)*8 + j
//   where k = t*32 + ct*16 + m, d = kc*32 + q*8 + j.
__global__ __launch_bounds__(256) void prep_swizzle(const float* __restrict__ w,
                                                    short* __restrict__ w_hi,
                                                    short* __restrict__ w_lo) {
    const int gid = blockIdx.x * 256 + threadIdx.x;
    const int k = gid >> 4, s = gid & 15;
    const float4 v = *(const float4*)(w + (size_t)k * DIM + s * 4);
    const int t = k >> 5, ct = (k >> 4) & 1, m = k & 15;
    const int kc = s >> 3, q = (s >> 1) & 3, j0 = (s & 1) * 4;
    const size_t fo =
        ((size_t)(((t * 2 + ct) * 2 + kc) * 4 + q) * 16 + m) * 8 + j0;
    float f[4] = {v.x, v.y, v.z, v.w};
    s16x4 hv, lv;
#pragma unroll
    for (int i = 0; i < 4; ++i) {
        short h = f2bf(f[i]);
        hv[i] = h;
        lv[i] = f2bf(f[i] - bf2f(h));
    }
    *(s16x4*)(w_hi + fo) = hv;
    *(s16x4*)(w_lo + fo) = lv;
}

// e2 by sequential fmaf (bit pattern the cleanup's exactness relies on);
// e2p = e2 + 0.5 is the biased constant for the packed-key argmin.
__global__ __launch_bounds__(256) void prep_e2(const float* __restrict__ w,
                                               float* __restrict__ e2,
                                               float* __restrict__ e2p) {
    int k = blockIdx.x * blockDim.x + threadIdx.x;
    if (k >= KCODES) return;
    const float* wk = w + (size_t)k * DIM;
    float s = 0.f;
#pragma unroll
    for (int d = 0; d < DIM; ++d) s = fmaf(wk[d], wk[d], s);
    e2[k] = s;
    e2p[k] = s + 0.5f;
}

// Block: 4 independent waves x 32 rows = 128 rows. No barriers in the K-loop.
__global__ __launch_bounds__(256, 2) void vq_main(
        const float* __restrict__ x, const float* __restrict__ w,
        const float* __restrict__ e2p,
        const short* __restrict__ w_hi, const short* __restrict__ w_lo,
        float* __restrict__ out_q, float* __restrict__ out_loss,
        float* __restrict__ out_idx,
        unsigned* __restrict__ flag_cnt, unsigned* __restrict__ flag_list) {
    const int tid = threadIdx.x;
    const int lane = tid & 63;
    const int wv = tid >> 6;
    const int m = lane & 15;
    const int q = lane >> 4;
    const int block_row0 = blockIdx.x * 128;
    const int wave_row0 = block_row0 + wv * 32;

    __shared__ int sidx[128];
    __shared__ unsigned char sflg[128];
    __shared__ float red[4];

    // ---- A operand: 2 rowtiles x 2 k-chunks; A[m][k=q*8+j] ----
    bf16x8 ah[2][2], al[2][2];
#pragma unroll
    for (int rt = 0; rt < 2; ++rt) {
        const float* xr = x + (size_t)(wave_row0 + rt * 16 + m) * DIM + q * 8;
        float xa[2][8];
        *(float4*)&xa[0][0] = *(const float4*)(xr);
        *(float4*)&xa[0][4] = *(const float4*)(xr + 4);
        *(float4*)&xa[1][0] = *(const float4*)(xr + 32);
        *(float4*)&xa[1][4] = *(const float4*)(xr + 36);
#pragma unroll
        for (int c = 0; c < 2; ++c)
#pragma unroll
            for (int j = 0; j < 8; ++j) {
                float f = xa[c][j];
                short h = f2bf(f);
                ah[rt][c][j] = h;
                al[rt][c][j] = f2bf(f - bf2f(h));
            }
    }

    unsigned best[2][4], sec[2][4];
#pragma unroll
    for (int rt = 0; rt < 2; ++rt)
#pragma unroll
        for (int r = 0; r < 4; ++r) { best[rt][r] = ~0u; sec[rt][r] = ~0u; }

    // Per-lane B pointers; tile stride 2048 shorts, frag stride 512.
    const short* ph = w_hi + q * 128 + m * 8;
    const short* pl = w_lo + q * 128 + m * 8;

    // Prime tile 0
    bf16x8 cbh[2][2], cbl[2][2];
    float ce[2];
#pragma unroll
    for (int ct = 0; ct < 2; ++ct)
#pragma unroll
        for (int kc = 0; kc < 2; ++kc) {
            cbh[ct][kc] = *(const bf16x8*)(ph + (ct * 2 + kc) * 512);
            cbl[ct][kc] = *(const bf16x8*)(pl + (ct * 2 + kc) * 512);
        }
    ce[0] = e2p[m];
    ce[1] = e2p[16 + m];

    unsigned id0 = (unsigned)m;   // code idx for (t, ct=0); ct=1 adds 16

    for (int t = 0; t < KCODES / 32; ++t) {
        // ---- prefetch tile t+1 (wraps at 31; harmless) ----
        const int tn = (t + 1) & 31;
        bf16x8 nbh[2][2], nbl[2][2];
        float ne[2];
#pragma unroll
        for (int ct = 0; ct < 2; ++ct)
#pragma unroll
            for (int kc = 0; kc < 2; ++kc) {
                int off = tn * 2048 + (ct * 2 + kc) * 512;
                nbh[ct][kc] = *(const bf16x8*)(ph + off);
                nbl[ct][kc] = *(const bf16x8*)(pl + off);
            }
        ne[0] = e2p[tn * 32 + m];
        ne[1] = e2p[tn * 32 + 16 + m];

        // ---- MFMA on current tile ----
        f32x4 acc[2][2];
#pragma unroll
        for (int rt = 0; rt < 2; ++rt)
#pragma unroll
            for (int ct = 0; ct < 2; ++ct) {
                f32x4 a = {0.f, 0.f, 0.f, 0.f};
                a = __builtin_amdgcn_mfma_f32_16x16x32_bf16(al[rt][0], cbh[ct][0], a, 0, 0, 0);
                a = __builtin_amdgcn_mfma_f32_16x16x32_bf16(ah[rt][0], cbl[ct][0], a, 0, 0, 0);
                a = __builtin_amdgcn_mfma_f32_16x16x32_bf16(ah[rt][0], cbh[ct][0], a, 0, 0, 0);
                a = __builtin_amdgcn_mfma_f32_16x16x32_bf16(al[rt][1], cbh[ct][1], a, 0, 0, 0);
                a = __builtin_amdgcn_mfma_f32_16x16x32_bf16(ah[rt][1], cbl[ct][1], a, 0, 0, 0);
                a = __builtin_amdgcn_mfma_f32_16x16x32_bf16(ah[rt][1], cbh[ct][1], a, 0, 0, 0);
                acc[rt][ct] = a;
            }

        // ---- packed-key argmin epilogue ----
#pragma unroll
        for (int rt = 0; rt < 2; ++rt)
#pragma unroll
            for (int ct = 0; ct < 2; ++ct) {
                float e2c = ce[ct];
                unsigned idc = id0 + (unsigned)(ct * 16);
#pragma unroll
                for (int r = 0; r < 4; ++r) {
                    float g = fmaf(-2.f, acc[rt][ct][r], e2c);  // > 0 always
                    unsigned kb = (__float_as_uint(g) & 0xFFFFFC00u) | idc;
                    unsigned mx = kb > best[rt][r] ? kb : best[rt][r];
                    sec[rt][r] = sec[rt][r] < mx ? sec[rt][r] : mx;
                    best[rt][r] = kb < best[rt][r] ? kb : best[rt][r];
                }
            }
        id0 += 32;

        // rotate prefetch
#pragma unroll
        for (int ct = 0; ct < 2; ++ct)
#pragma unroll
            for (int kc = 0; kc < 2; ++kc) {
                cbh[ct][kc] = nbh[ct][kc];
                cbl[ct][kc] = nbl[ct][kc];
            }
        ce[0] = ne[0];
        ce[1] = ne[1];
    }

    // cross-lane min over the 16 m-lanes (same q group)
#pragma unroll
    for (int off = 1; off < 16; off <<= 1)
#pragma unroll
        for (int rt = 0; rt < 2; ++rt)
#pragma unroll
            for (int r = 0; r < 4; ++r) {
                unsigned ob = (unsigned)__shfl_xor((int)best[rt][r], off, 64);
                unsigned os = (unsigned)__shfl_xor((int)sec[rt][r], off, 64);
                unsigned mx = ob > best[rt][r] ? ob : best[rt][r];
                unsigned s2 = sec[rt][r] < os ? sec[rt][r] : os;
                sec[rt][r] = s2 < mx ? s2 : mx;
                best[rt][r] = ob < best[rt][r] ? ob : best[rt][r];
            }

    if (m == 0) {
#pragma unroll
        for (int rt = 0; rt < 2; ++rt)
#pragma unroll
            for (int r = 0; r < 4; ++r) {
                int lr = wv * 32 + rt * 16 + q * 4 + r;
                unsigned bk = best[rt][r], sk = sec[rt][r];
                int bi = (int)(bk & 1023u);
                float bf = __uint_as_float(bk & 0xFFFFFC00u);
                float sf = __uint_as_float(sk & 0xFFFFFC00u);
                bool fl = (sf - bf) < MARGIN;
                sidx[lr] = bi;
                sflg[lr] = fl ? 1 : 0;
                if (fl) {
                    unsigned p = atomicAdd(flag_cnt, 1u);
                    flag_list[p] = (unsigned)(block_row0 + lr);
                }
            }
    }
    __syncthreads();

    // ---- output pass: 2 x 64 rows, 4 threads/row ----
    float lsum = 0.f;
    const int rl = tid >> 2, part = tid & 3;
#pragma unroll
    for (int p = 0; p < 2; ++p) {
        int lr = p * 64 + rl;
        int grow = block_row0 + lr;
        if (!sflg[lr]) {
            int bi = sidx[lr];
            const float* xs = x + (size_t)grow * DIM + part * 16;
            const float* ws = w + (size_t)bi * DIM + part * 16;
            float* os = out_q + (size_t)grow * DIM + part * 16;
#pragma unroll
            for (int i = 0; i < 4; ++i) {
                float4 xv = *(const float4*)(xs + 4 * i);
                float4 wv4 = *(const float4*)(ws + 4 * i);
                float d0 = wv4.x - xv.x, d1 = wv4.y - xv.y;
                float d2 = wv4.z - xv.z, d3 = wv4.w - xv.w;
                lsum = fmaf(d0, d0, lsum);
                lsum = fmaf(d1, d1, lsum);
                lsum = fmaf(d2, d2, lsum);
                lsum = fmaf(d3, d3, lsum);
                float4 o = {xv.x + d0, xv.y + d1, xv.z + d2, xv.w + d3};
                *(float4*)(os + 4 * i) = o;
            }
            if (part == 0) out_idx[grow] = (float)bi;
        }
    }

    for (int off = 32; off > 0; off >>= 1) lsum += __shfl_down(lsum, off, 64);
    if ((tid & 63) == 0) red[tid >> 6] = lsum;
    __syncthreads();
    if (tid == 0) {
        float s = (red[0] + red[1]) + (red[2] + red[3]);
        atomicAdd(out_loss, s * LOSS_SCALE);
    }
}

// Exact re-scan: ONE WAVE PER FLAGGED ROW, no LDS. Each lane owns 16 codes,
// scanned SEQUENTIALLY (unroll 2) to keep the live set ~120 VGPRs — no spill.
// u64 (dist,idx) key min across lanes = numpy first-index argmin. Bit-exact.
__global__ __launch_bounds__(256) void vq_cleanup(
        const float* __restrict__ x, const float* __restrict__ w,
        const float* __restrict__ e2,
        const unsigned* __restrict__ flag_cnt,
        const unsigned* __restrict__ flag_list,
        float* __restrict__ out_q, float* __restrict__ out_loss,
        float* __restrict__ out_idx) {
    const int lane = threadIdx.x & 63;
    const unsigned gw = blockIdx.x * 4 + (threadIdx.x >> 6);
    const unsigned nw = gridDim.x * 4;
    const unsigned cnt = *flag_cnt;

    for (unsigned i = gw; i < cnt; i += nw) {
        const int row = (int)__builtin_amdgcn_readfirstlane((int)flag_list[i]);
        const float* xr = x + (size_t)row * DIM;

        // cache x row: 16 float4 = 64 VGPRs, lives across the code loop
        float4 xv[16];
#pragma unroll
        for (int d4 = 0; d4 < 16; ++d4) xv[d4] = *(const float4*)(xr + d4 * 4);

        // x2: sequential-d fmaf (bit pattern matches reference path)
        float x2 = 0.f;
#pragma unroll
        for (int d4 = 0; d4 < 16; ++d4) {
            x2 = fmaf(xv[d4].x, xv[d4].x, x2);
            x2 = fmaf(xv[d4].y, xv[d4].y, x2);
            x2 = fmaf(xv[d4].z, xv[d4].z, x2);
            x2 = fmaf(xv[d4].w, xv[d4].w, x2);
        }

        unsigned long long kmin = ~0ULL;
        const int k0 = lane * 16;
#pragma unroll 2
        for (int c = 0; c < 16; ++c) {
            const int code = k0 + c;
            const float* wc = w + (size_t)code * DIM;
            float dot = 0.f;
#pragma unroll
            for (int d4 = 0; d4 < 16; ++d4) {
                float4 wv4 = *(const float4*)(wc + d4 * 4);
                dot = fmaf(wv4.x, xv[d4].x, dot);
                dot = fmaf(wv4.y, xv[d4].y, dot);
                dot = fmaf(wv4.z, xv[d4].z, dot);
                dot = fmaf(wv4.w, xv[d4].w, dot);
            }
            float dist = (x2 + e2[code]) - 2.0f * dot;
            unsigned long long key =
                ((unsigned long long)__float_as_uint(dist) << 32) |
                (unsigned)code;
            kmin = kmin < key ? kmin : key;
        }
        // full-wave butterfly min
#pragma unroll
        for (int off = 1; off < 64; off <<= 1) {
            unsigned long long o = __shfl_xor(kmin, off, 64);
            kmin = kmin < o ? kmin : o;
        }
        const int bi = (int)(unsigned)(kmin & 0xFFFFFFFFu);

        if (lane < 16) {
            float4 x4 = xv[lane];
            float4 w4 = *(const float4*)(w + (size_t)bi * DIM + lane * 4);
            float d0 = w4.x - x4.x, d1 = w4.y - x4.y;
            float d2 = w4.z - x4.z, d3 = w4.w - x4.w;
            float ls = 0.f;
            ls = fmaf(d0, d0, ls);
            ls = fmaf(d1, d1, ls);
            ls = fmaf(d2, d2, ls);
            ls = fmaf(d3, d3, ls);
            float4 o = {x4.x + d0, x4.y + d1, x4.z + d2, x4.w + d3};
            *(float4*)(out_q + (size_t)row * DIM + lane * 4) = o;
#pragma unroll
            for (int off = 1; off < 16; off <<= 1)
                ls += __shfl_xor(ls, off, 64);
            if (lane == 0) {
                out_idx[row] = (float)bi;
                atomicAdd(out_loss, ls * LOSS_SCALE);
            }
        }
    }
}

extern "C" void kernel_launch(void* const* d_in, const int* in_sizes, int n_in,
                              void* d_out, int out_size, void* d_ws, size_t ws_size,
                              hipStream_t stream) {
    const float* x = (const float*)d_in[0];   // [N, D]
    const float* w = (const float*)d_in[1];   // [K, D]

    float* out_q    = (float*)d_out;
    float* out_loss = (float*)d_out + (size_t)NROWS * DIM;
    float* out_idx  = out_loss + 1;

    // ws: e2 (4KB) | e2p (4KB) | w_hi (128KB) | w_lo (128KB) | cnt | list
    float* e2 = (float*)d_ws;
    float* e2p = e2 + KCODES;
    short* w_hi = (short*)(e2p + KCODES);
    short* w_lo = w_hi + (size_t)KCODES * DIM;
    unsigned* cnt = (unsigned*)(w_lo + (size_t)KCODES * DIM);
    unsigned* list = cnt + 1;

    hipMemsetAsync(out_loss, 0, sizeof(float), stream);
    hipMemsetAsync(cnt, 0, sizeof(unsigned), stream);

    prep_swizzle<<<KCODES * 16 / 256, 256, 0, stream>>>(w, w_hi, w_lo);
    prep_e2<<<(KCODES + 255) / 256, 256, 0, stream>>>(w, e2, e2p);
    vq_main<<<NROWS / 128, 256, 0, stream>>>(x, w, e2p, w_hi, w_lo,
                                             out_q, out_loss, out_idx, cnt, list);
    vq_cleanup<<<2048, 256, 0, stream>>>(x, w, e2, cnt, list,
                                         out_q, out_loss, out_idx);
}

// Round 9
// 283.812 us; speedup vs baseline: 2.5319x; 1.4039x over previous
//
#include <hip/hip_runtime.h>

// VectorQuantizer forward: N=131072 rows of D=64 vs K=1024 codes.
// Outputs flat fp32: [quantized_st (N*D), loss (1), indices-as-float (N)].
//
// Two-tier exactness scheme (float-gap variant validated round 5, absmax 0):
//  - vq_main: bf16 hi/lo split MFMA approx of g[k] = e2[k] - 2*dot (row-const
//    x2 dropped). FLOAT lexicographic (g, idx) argmin -> numpy first-index
//    rule. Rows with (sec - best) < MARGIN (5e-5) flagged; approx err ~2e-6
//    so unflagged rows' exact argmin == approx argmin.
//    NO bit-masked keys (round-6/8 lesson: 10-bit mask grid 6.1e-5 ~= bulk
//    dist spacing -> flag explosion).
//  - vq_cleanup: one wave per flagged row, bit-exact reference numerics
//    (sequential fmaf dot d=0..63, (x2+e2)-2*dot, u64 (dist,idx) key min).
//    Code loop NOT fully unrolled (round-7 lesson: spill at 256 VGPR).
// Main K-loop: no LDS/barriers; B pre-swizzled to MFMA frag order; 64 rows
// per wave so each 8-load tile feeds 48 MFMAs (halves L2 traffic vs 32-row).

#define NROWS 131072
#define DIM 64
#define KCODES 1024
#define MARGIN 5e-5f
#define LOSS_SCALE (1.25f / ((float)NROWS * (float)DIM))

typedef short bf16x8 __attribute__((ext_vector_type(8)));
typedef short s16x4 __attribute__((ext_vector_type(4)));
typedef float f32x4 __attribute__((ext_vector_type(4)));

__device__ __forceinline__ short f2bf(float f) {
    unsigned u = __float_as_uint(f);
    u += 0x7FFF + ((u >> 16) & 1);   // RNE
    return (short)(u >> 16);
}
__device__ __forceinline__ float bf2f(short h) {
    return __uint_as_float(((unsigned)(unsigned short)h) << 16);
}

// One prep kernel: bf16 hi/lo swizzle into MFMA B-frag order (16 thr/code,
// coalesced), e2 by sequential fmaf via LDS-staged row, zero loss/flag_cnt.
//   frag short index = ((((t*2+ct)*2+kc)*4+q)*16 + m)*8 + j
//   where k = t*32 + ct*16 + m, d = kc*32 + q*8 + j.
__global__ __launch_bounds__(256) void prep(const float* __restrict__ w,
                                            float* __restrict__ e2,
                                            short* __restrict__ w_hi,
                                            short* __restrict__ w_lo,
                                            float* __restrict__ out_loss,
                                            unsigned* __restrict__ flag_cnt) {
    __shared__ float sx[16][65];   // +1 pad: conflict-free column reads
    const int gid = blockIdx.x * 256 + threadIdx.x;
    const int code = gid >> 4, s = gid & 15;
    const int cib = threadIdx.x >> 4;
    const float4 v = *(const float4*)(w + (size_t)code * DIM + s * 4);
    *(float4*)&sx[cib][s * 4] = v;

    const int t = code >> 5, ct = (code >> 4) & 1, m = code & 15;
    const int kc = s >> 3, q = (s >> 1) & 3, j0 = (s & 1) * 4;
    const size_t fo =
        ((size_t)(((t * 2 + ct) * 2 + kc) * 4 + q) * 16 + m) * 8 + j0;
    float f[4] = {v.x, v.y, v.z, v.w};
    s16x4 hv, lv;
#pragma unroll
    for (int i = 0; i < 4; ++i) {
        short h = f2bf(f[i]);
        hv[i] = h;
        lv[i] = f2bf(f[i] - bf2f(h));
    }
    *(s16x4*)(w_hi + fo) = hv;
    *(s16x4*)(w_lo + fo) = lv;

    __syncthreads();
    if (s == 0) {   // sequential-d fmaf: bit pattern the cleanup relies on
        float acc = 0.f;
#pragma unroll
        for (int d = 0; d < DIM; ++d) acc = fmaf(sx[cib][d], sx[cib][d], acc);
        e2[code] = acc;
    }
    if (gid == 0) { *out_loss = 0.f; *flag_cnt = 0u; }
}

// Block: 4 independent waves x 64 rows = 256 rows. No barriers in the K-loop.
__global__ __launch_bounds__(256, 2) void vq_main(
        const float* __restrict__ x, const float* __restrict__ w,
        const float* __restrict__ e2,
        const short* __restrict__ w_hi, const short* __restrict__ w_lo,
        float* __restrict__ out_q, float* __restrict__ out_loss,
        float* __restrict__ out_idx,
        unsigned* __restrict__ flag_cnt, unsigned* __restrict__ flag_list) {
    const int tid = threadIdx.x;
    const int lane = tid & 63;
    const int wv = tid >> 6;
    const int m = lane & 15;
    const int q = lane >> 4;
    const int block_row0 = blockIdx.x * 256;
    const int wave_row0 = block_row0 + wv * 64;

    __shared__ int sidx[256];
    __shared__ unsigned char sflg[256];
    __shared__ float red[4];

    // ---- A operand: 4 rowtiles x 2 k-chunks; A[m][k=q*8+j] ----
    bf16x8 ah[4][2], al[4][2];
#pragma unroll
    for (int rt = 0; rt < 4; ++rt) {
        const float* xr = x + (size_t)(wave_row0 + rt * 16 + m) * DIM + q * 8;
        float xa[2][8];
        *(float4*)&xa[0][0] = *(const float4*)(xr);
        *(float4*)&xa[0][4] = *(const float4*)(xr + 4);
        *(float4*)&xa[1][0] = *(const float4*)(xr + 32);
        *(float4*)&xa[1][4] = *(const float4*)(xr + 36);
#pragma unroll
        for (int c = 0; c < 2; ++c)
#pragma unroll
            for (int j = 0; j < 8; ++j) {
                float f = xa[c][j];
                short h = f2bf(f);
                ah[rt][c][j] = h;
                al[rt][c][j] = f2bf(f - bf2f(h));
            }
    }

    float best[4][4], sec[4][4];
    int bidx[4][4];
#pragma unroll
    for (int rt = 0; rt < 4; ++rt)
#pragma unroll
        for (int r = 0; r < 4; ++r) {
            best[rt][r] = 3.4e38f;
            sec[rt][r] = 3.4e38f;
            bidx[rt][r] = 0;
        }

    // Per-lane B pointers; tile stride 2048 shorts, frag stride 512.
    const short* ph = w_hi + q * 128 + m * 8;
    const short* pl = w_lo + q * 128 + m * 8;

    // Prime tile 0
    bf16x8 cbh[2][2], cbl[2][2];
    float ce[2];
#pragma unroll
    for (int ct = 0; ct < 2; ++ct)
#pragma unroll
        for (int kc = 0; kc < 2; ++kc) {
            cbh[ct][kc] = *(const bf16x8*)(ph + (ct * 2 + kc) * 512);
            cbl[ct][kc] = *(const bf16x8*)(pl + (ct * 2 + kc) * 512);
        }
    ce[0] = e2[m];
    ce[1] = e2[16 + m];

    for (int t = 0; t < KCODES / 32; ++t) {
        // ---- prefetch tile t+1 (wraps at 31; harmless) ----
        const int tn = (t + 1) & 31;
        bf16x8 nbh[2][2], nbl[2][2];
        float ne[2];
#pragma unroll
        for (int ct = 0; ct < 2; ++ct)
#pragma unroll
            for (int kc = 0; kc < 2; ++kc) {
                int off = tn * 2048 + (ct * 2 + kc) * 512;
                nbh[ct][kc] = *(const bf16x8*)(ph + off);
                nbl[ct][kc] = *(const bf16x8*)(pl + off);
            }
        ne[0] = e2[tn * 32 + m];
        ne[1] = e2[tn * 32 + 16 + m];

        // ---- MFMA + immediate epilogue per (rt, ct): small acc live range,
        //      MFMA chain of the next acc overlaps this one's VALU ----
#pragma unroll
        for (int rt = 0; rt < 4; ++rt)
#pragma unroll
            for (int ct = 0; ct < 2; ++ct) {
                f32x4 a = {0.f, 0.f, 0.f, 0.f};
                a = __builtin_amdgcn_mfma_f32_16x16x32_bf16(al[rt][0], cbh[ct][0], a, 0, 0, 0);
                a = __builtin_amdgcn_mfma_f32_16x16x32_bf16(ah[rt][0], cbl[ct][0], a, 0, 0, 0);
                a = __builtin_amdgcn_mfma_f32_16x16x32_bf16(ah[rt][0], cbh[ct][0], a, 0, 0, 0);
                a = __builtin_amdgcn_mfma_f32_16x16x32_bf16(al[rt][1], cbh[ct][1], a, 0, 0, 0);
                a = __builtin_amdgcn_mfma_f32_16x16x32_bf16(ah[rt][1], cbl[ct][1], a, 0, 0, 0);
                a = __builtin_amdgcn_mfma_f32_16x16x32_bf16(ah[rt][1], cbh[ct][1], a, 0, 0, 0);

                const float e2c = ce[ct];
                const int id = t * 32 + ct * 16 + m;
#pragma unroll
                for (int r = 0; r < 4; ++r) {
                    float g = fmaf(-2.f, a[r], e2c);
                    float mx = fmaxf(g, best[rt][r]);
                    sec[rt][r] = fminf(sec[rt][r], mx);
                    bool c = g < best[rt][r];
                    best[rt][r] = c ? g : best[rt][r];
                    bidx[rt][r] = c ? id : bidx[rt][r];
                }
            }

        // rotate prefetch
#pragma unroll
        for (int ct = 0; ct < 2; ++ct)
#pragma unroll
            for (int kc = 0; kc < 2; ++kc) {
                cbh[ct][kc] = nbh[ct][kc];
                cbl[ct][kc] = nbl[ct][kc];
            }
        ce[0] = ne[0];
        ce[1] = ne[1];
    }

    // cross-lane lex reduce over the 16 m-lanes; tie -> lower idx (numpy rule)
#pragma unroll
    for (int off = 1; off < 16; off <<= 1)
#pragma unroll
        for (int rt = 0; rt < 4; ++rt)
#pragma unroll
            for (int r = 0; r < 4; ++r) {
                float ob = __shfl_xor(best[rt][r], off, 64);
                int oi = __shfl_xor(bidx[rt][r], off, 64);
                float os = __shfl_xor(sec[rt][r], off, 64);
                float mx = fmaxf(best[rt][r], ob);
                sec[rt][r] = fminf(fminf(sec[rt][r], os), mx);
                bool take = (ob < best[rt][r]) ||
                            (ob == best[rt][r] && oi < bidx[rt][r]);
                if (take) { best[rt][r] = ob; bidx[rt][r] = oi; }
            }

    if (m == 0) {
#pragma unroll
        for (int rt = 0; rt < 4; ++rt)
#pragma unroll
            for (int r = 0; r < 4; ++r) {
                int lr = wv * 64 + rt * 16 + q * 4 + r;
                sidx[lr] = bidx[rt][r];
                bool fl = (sec[rt][r] - best[rt][r]) < MARGIN;
                sflg[lr] = fl ? 1 : 0;
                if (fl) {
                    unsigned p = atomicAdd(flag_cnt, 1u);
                    flag_list[p] = (unsigned)(block_row0 + lr);
                }
            }
    }
    __syncthreads();

    // ---- output pass: 4 x 64 rows, 4 threads/row ----
    float lsum = 0.f;
    const int rl = tid >> 2, part = tid & 3;
#pragma unroll
    for (int p = 0; p < 4; ++p) {
        int lr = p * 64 + rl;
        int grow = block_row0 + lr;
        if (!sflg[lr]) {
            int bi = sidx[lr];
            const float* xs = x + (size_t)grow * DIM + part * 16;
            const float* ws = w + (size_t)bi * DIM + part * 16;
            float* os = out_q + (size_t)grow * DIM + part * 16;
#pragma unroll
            for (int i = 0; i < 4; ++i) {
                float4 xv = *(const float4*)(xs + 4 * i);
                float4 wv4 = *(const float4*)(ws + 4 * i);
                float d0 = wv4.x - xv.x, d1 = wv4.y - xv.y;
                float d2 = wv4.z - xv.z, d3 = wv4.w - xv.w;
                lsum = fmaf(d0, d0, lsum);
                lsum = fmaf(d1, d1, lsum);
                lsum = fmaf(d2, d2, lsum);
                lsum = fmaf(d3, d3, lsum);
                float4 o = {xv.x + d0, xv.y + d1, xv.z + d2, xv.w + d3};
                *(float4*)(os + 4 * i) = o;
            }
            if (part == 0) out_idx[grow] = (float)bi;
        }
    }

    for (int off = 32; off > 0; off >>= 1) lsum += __shfl_down(lsum, off, 64);
    if ((tid & 63) == 0) red[tid >> 6] = lsum;
    __syncthreads();
    if (tid == 0) {
        float s = (red[0] + red[1]) + (red[2] + red[3]);
        atomicAdd(out_loss, s * LOSS_SCALE);
    }
}

// Exact re-scan: one wave per flagged row. Each lane owns 16 codes, scanned
// sequentially (unroll 2; full unroll spills — round-7 lesson). Bit-exact
// numerics; u64 (dist,idx) key min = numpy first-index argmin.
__global__ __launch_bounds__(256) void vq_cleanup(
        const float* __restrict__ x, const float* __restrict__ w,
        const float* __restrict__ e2,
        const unsigned* __restrict__ flag_cnt,
        const unsigned* __restrict__ flag_list,
        float* __restrict__ out_q, float* __restrict__ out_loss,
        float* __restrict__ out_idx) {
    const int lane = threadIdx.x & 63;
    const unsigned gw = blockIdx.x * 4 + (threadIdx.x >> 6);
    const unsigned nw = gridDim.x * 4;
    const unsigned cnt = *flag_cnt;

    for (unsigned i = gw; i < cnt; i += nw) {
        const int row = (int)__builtin_amdgcn_readfirstlane((int)flag_list[i]);
        const float* xr = x + (size_t)row * DIM;

        float4 xv[16];
#pragma unroll
        for (int d4 = 0; d4 < 16; ++d4) xv[d4] = *(const float4*)(xr + d4 * 4);

        float x2 = 0.f;
#pragma unroll
        for (int d4 = 0; d4 < 16; ++d4) {
            x2 = fmaf(xv[d4].x, xv[d4].x, x2);
            x2 = fmaf(xv[d4].y, xv[d4].y, x2);
            x2 = fmaf(xv[d4].z, xv[d4].z, x2);
            x2 = fmaf(xv[d4].w, xv[d4].w, x2);
        }

        unsigned long long kmin = ~0ULL;
        const int k0 = lane * 16;
#pragma unroll 2
        for (int c = 0; c < 16; ++c) {
            const int code = k0 + c;
            const float* wc = w + (size_t)code * DIM;
            float dot = 0.f;
#pragma unroll
            for (int d4 = 0; d4 < 16; ++d4) {
                float4 wv4 = *(const float4*)(wc + d4 * 4);
                dot = fmaf(wv4.x, xv[d4].x, dot);
                dot = fmaf(wv4.y, xv[d4].y, dot);
                dot = fmaf(wv4.z, xv[d4].z, dot);
                dot = fmaf(wv4.w, xv[d4].w, dot);
            }
            float dist = (x2 + e2[code]) - 2.0f * dot;
            unsigned long long key =
                ((unsigned long long)__float_as_uint(dist) << 32) |
                (unsigned)code;
            kmin = kmin < key ? kmin : key;
        }
#pragma unroll
        for (int off = 1; off < 64; off <<= 1) {
            unsigned long long o = __shfl_xor(kmin, off, 64);
            kmin = kmin < o ? kmin : o;
        }
        const int bi = (int)(unsigned)(kmin & 0xFFFFFFFFu);

        if (lane < 16) {
            float4 x4 = xv[lane];
            float4 w4 = *(const float4*)(w + (size_t)bi * DIM + lane * 4);
            float d0 = w4.x - x4.x, d1 = w4.y - x4.y;
            float d2 = w4.z - x4.z, d3 = w4.w - x4.w;
            float ls = 0.f;
            ls = fmaf(d0, d0, ls);
            ls = fmaf(d1, d1, ls);
            ls = fmaf(d2, d2, ls);
            ls = fmaf(d3, d3, ls);
            float4 o = {x4.x + d0, x4.y + d1, x4.z + d2, x4.w + d3};
            *(float4*)(out_q + (size_t)row * DIM + lane * 4) = o;
#pragma unroll
            for (int off = 1; off < 16; off <<= 1)
                ls += __shfl_xor(ls, off, 64);
            if (lane == 0) {
                out_idx[row] = (float)bi;
                atomicAdd(out_loss, ls * LOSS_SCALE);
            }
        }
    }
}

extern "C" void kernel_launch(void* const* d_in, const int* in_sizes, int n_in,
                              void* d_out, int out_size, void* d_ws, size_t ws_size,
                              hipStream_t stream) {
    const float* x = (const float*)d_in[0];   // [N, D]
    const float* w = (const float*)d_in[1];   // [K, D]

    float* out_q    = (float*)d_out;
    float* out_loss = (float*)d_out + (size_t)NROWS * DIM;
    float* out_idx  = out_loss + 1;

    // ws: e2 (4KB) | w_hi frag-order (128KB) | w_lo (128KB) | cnt | list
    float* e2 = (float*)d_ws;
    short* w_hi = (short*)(e2 + KCODES);
    short* w_lo = w_hi + (size_t)KCODES * DIM;
    unsigned* cnt = (unsigned*)(w_lo + (size_t)KCODES * DIM);
    unsigned* list = cnt + 1;

    prep<<<KCODES * 16 / 256, 256, 0, stream>>>(w, e2, w_hi, w_lo,
                                                out_loss, cnt);
    vq_main<<<NROWS / 256, 256, 0, stream>>>(x, w, e2, w_hi, w_lo,
                                             out_q, out_loss, out_idx, cnt, list);
    vq_cleanup<<<2048, 256, 0, stream>>>(x, w, e2, cnt, list,
                                         out_q, out_loss, out_idx);
}